// Round 9
// baseline (588.927 us; speedup 1.0000x reference)
//
#include <hip/hip_runtime.h>

typedef _Float16 half8 __attribute__((ext_vector_type(8)));
typedef _Float16 half4 __attribute__((ext_vector_type(4)));
typedef _Float16 half2 __attribute__((ext_vector_type(2)));
typedef float floatx4 __attribute__((ext_vector_type(4)));

union H8 { half8 h8; half4 h4[2]; half2 h2[4]; int i[4]; };

__device__ __forceinline__ int packh2(float a, float b) {
    union { _Float16 h[2]; int i; } u;
    u.h[0] = (_Float16)a; u.h[1] = (_Float16)b;
    return u.i;
}

__device__ __forceinline__ floatx4 unpack4(int lo, int hi) {
    union { int i; _Float16 h[2]; } a, b;
    a.i = lo; b.i = hi;
    floatx4 r = {(float)a.h[0], (float)a.h[1], (float)b.h[0], (float)b.h[1]};
    return r;
}

// Gather a half8 A-fragment from per-lane packed P pairs (proven P-repack path).
__device__ __forceinline__ half8 gather8(int idxA, int idxB, bool sel,
                                         int A0, int A1, int B0, int B1) {
    int a0 = __builtin_amdgcn_ds_bpermute(idxA, A0);
    int b0 = __builtin_amdgcn_ds_bpermute(idxA, B0);
    int a1 = __builtin_amdgcn_ds_bpermute(idxA, A1);
    int b1 = __builtin_amdgcn_ds_bpermute(idxA, B1);
    int a2 = __builtin_amdgcn_ds_bpermute(idxB, A0);
    int b2 = __builtin_amdgcn_ds_bpermute(idxB, B0);
    int a3 = __builtin_amdgcn_ds_bpermute(idxB, A1);
    int b3 = __builtin_amdgcn_ds_bpermute(idxB, B1);
    H8 u;
    u.i[0] = sel ? b0 : a0;
    u.i[1] = sel ? b1 : a1;
    u.i[2] = sel ? b2 : a2;
    u.i[3] = sel ? b3 : a3;
    return u.h8;
}

// Problem constants: B=4096 windows, N=64 tokens (8x8), C=192, NH=6, HD=32, KS=5
//
// ws layout (bytes) -- everything pre-swizzled into MFMA fragment order:
//   WtF  : f16 [48 nt][6 ks][64 lane][8]  @ 0       (294912 B)  qkv weights (B-frags)
//   PtF  : f16 [12 nt][6 ks][64 lane][8]  @ 294912  ( 73728 B)  proj weights (B-frags)
//   biasF: f32 [6 h][4 mt'][4 ntq][64 lane][4 r] @ 368640 (98304 B)  attn bias in S^T C-frag order
//   dwF  : f16 [6 g][4 kq][25 tap][8 ch]  @ 466944  (  9600 B)  depthwise weights
//   dwbF : f16 [6 g][4 kq][8 ch]          @ 476544  (   384 B)  depthwise bias
//   pwF  : f16 [6 g][2 ntc][64 lane][8]   @ 476928  ( 12288 B)  1x1 grouped weights (B-frags)

__global__ __launch_bounds__(512) void prep_kernel(
    const float* __restrict__ wq, const float* __restrict__ wkv,
    const float* __restrict__ proj_w, const float* __restrict__ rpb,
    const int* __restrict__ rel,
    const float* __restrict__ dw_w, const float* __restrict__ dw_b,
    const float* __restrict__ pw_w,
    _Float16* __restrict__ WtF, _Float16* __restrict__ PtF,
    float* __restrict__ biasF, _Float16* __restrict__ dwF,
    _Float16* __restrict__ dwbF, _Float16* __restrict__ pwF)
{
    int idx = blockIdx.x * 512 + threadIdx.x;
    if (idx < 147456) {                                   // WtF
        int j = idx & 7, lane = (idx >> 3) & 63, t = idx >> 9;
        int ks = t % 6, nt = t / 6;
        int k = ks * 32 + (lane >> 4) * 8 + j;
        int n = nt * 16 + (lane & 15);
        float v = (n < 192) ? wq[k * 192 + n] : wkv[k * 576 + (n - 192)];
        WtF[idx] = (_Float16)v;
    } else if (idx < 184320) {                            // PtF
        int i2 = idx - 147456;
        int j = i2 & 7, lane = (i2 >> 3) & 63, t = i2 >> 9;
        int ks = t % 6, nt = t / 6;
        int k = ks * 32 + (lane >> 4) * 8 + j;
        int n = nt * 16 + (lane & 15);
        PtF[i2] = (_Float16)proj_w[k * 192 + n];
    } else if (idx < 208896) {                            // biasF (f32)
        int i2 = idx - 184320;
        int r = i2 & 3, lane = (i2 >> 2) & 63, t = i2 >> 8;
        int ntq = t & 3, mt = (t >> 2) & 3, h = t >> 4;
        int m = mt * 16 + (lane >> 4) * 4 + r;            // key token (S^T row)
        int n = ntq * 16 + (lane & 15);                   // query token (S^T col)
        biasF[i2] = rpb[rel[n * 64 + m] * 6 + h];
    } else if (idx < 213696) {                            // dwF
        int i2 = idx - 208896;
        int j = i2 & 7, t = i2 >> 3;
        int tap = t % 25, gk = t / 25;
        int c = (gk >> 2) * 32 + (gk & 3) * 8 + j;
        dwF[i2] = (_Float16)dw_w[c * 25 + tap];
    } else if (idx < 213888) {                            // dwbF
        int i2 = idx - 213696;
        int j = i2 & 7, gk = i2 >> 3;
        int c = (gk >> 2) * 32 + (gk & 3) * 8 + j;
        dwbF[i2] = (_Float16)dw_b[c];
    } else if (idx < 220032) {                            // pwF
        int i2 = idx - 213888;
        int j = i2 & 7, lane = (i2 >> 3) & 63, t = i2 >> 9;
        int ntc = t & 1, g = t >> 1;
        int oc = g * 32 + ntc * 16 + (lane & 15);
        int ic = (lane >> 4) * 8 + j;
        pwF[i2] = (_Float16)pw_w[oc * 32 + ic];
    }
}

// TWO WINDOWS PER BLOCK (768 threads = 12 waves = forced 3 waves/SIMD on one CU).
// Waves 0-5 -> window 2b, waves 6-11 -> window 2b+1, each in its own LDS partition.
//
// Per-window LDS partition (_Float16 units, stride WSTR = 33288):
//  sX   [64][200] @ 0      (12800 h) x staged f16
//  sVR  [64][200] @ 12800  (12800 h) v_r[n][c] per-wave stripe; conv output + out_pre land here too
//  sS   6 x 1280  @ 25600  ( 7680 h) per-wave scratch: Q/K [32][40]; V per-d-half [16][72] (reused)
//  zero16         @ 33280  (8 h)
// total = 2 x 33288 h = 133152 B, STATIC allocation.
//
// STATIC __shared__ is the fix for the whole-session VGPR-84 pathology:
// with extern __shared__ the backend sees LDS=0, assumes 6-8 waves/EU are
// reachable, squeezes to 84 VGPRs and spills (~25 regs -> +400 MB HBM).
// With the 133152-B array visible at compile time it knows only ONE block
// (3 waves/EU) can ever be resident -> register budget ~170 -> natural
// pressure ~110 allocates cleanly, zero spill.

#define WSTR 33288
#define XO   0
#define VRO  12800
#define SCR  25600
#define ZO   33280

__global__ __launch_bounds__(768) void wa_main(
    const float* __restrict__ xg,
    const float* __restrict__ bq, const float* __restrict__ bkv,
    const float* __restrict__ proj_bg, const float* __restrict__ pw_b,
    const _Float16* __restrict__ WtF, const _Float16* __restrict__ PtF,
    const float* __restrict__ biasF,
    const _Float16* __restrict__ dwF, const _Float16* __restrict__ dwbF,
    const _Float16* __restrict__ pwF,
    float* __restrict__ outg)
{
    __shared__ _Float16 smem[2 * WSTR];   // 133152 B static LDS

    const int tid  = threadIdx.x;
    const int lane = tid & 63;
    const int wvid = tid >> 6;          // 0..11
    const int w    = (wvid >= 6) ? 1 : 0;   // window slot within block
    const int h    = wvid - 6 * w;      // head 0..5
    const int b2   = blockIdx.x * 2 + w;
    const int tw   = tid - w * 384;     // thread id within window group
    const int mrow = lane & 15;
    const int kq   = lane >> 4;
    const float scale = 0.17677669529663687f;   // 32^-0.5

    _Float16* sHalf = smem + w * WSTR;          // this window's partition
    _Float16* sS = sHalf + SCR + h * 1280;      // this wave's scratch

    // ---------------- Phase 0: stage x -> f16 LDS; zero page ----------------
    const float* xb = xg + (size_t)b2 * 12288;
    #pragma unroll
    for (int it = 0; it < 8; ++it) {
        int f4  = it * 384 + tw;
        int row = f4 / 48;
        int col = (f4 % 48) * 4;
        float4 v = ((const float4*)xb)[f4];
        half4 p;
        p[0] = (_Float16)v.x; p[1] = (_Float16)v.y;
        p[2] = (_Float16)v.z; p[3] = (_Float16)v.w;
        *(half4*)(sHalf + XO + row * 200 + col) = p;
    }
    if (tw < 8) sHalf[ZO + tw] = (_Float16)0.0f;
    __syncthreads();   // barrier 1 (both windows; identical work -> minimal skew)

    // ---------------- Phase 1a: v_r (swapped mfma -> transposed D -> half4 stores) ----------------
    #pragma unroll
    for (int t = 0; t < 2; ++t) {
        int nt = 36 + 2 * h + t;
        half8 bf[6];
        #pragma unroll
        for (int ks = 0; ks < 6; ++ks)
            bf[ks] = ((const half8*)WtF)[(nt * 6 + ks) * 64 + lane];
        float4 b4 = *(const float4*)(bkv + nt * 16 - 192 + kq * 4);
        floatx4 binit = {b4.x, b4.y, b4.z, b4.w};
        #pragma unroll
        for (int mt4 = 0; mt4 < 4; ++mt4) {
            floatx4 acc = binit;
            #pragma unroll
            for (int ks = 0; ks < 6; ++ks) {
                half8 af = *(const half8*)(sHalf + XO + (mt4 * 16 + mrow) * 200 + ks * 32 + kq * 8);
                acc = __builtin_amdgcn_mfma_f32_16x16x32_f16(bf[ks], af, acc, 0, 0, 0);
            }
            union { int i2[2]; half4 h4; } u;
            u.i2[0] = packh2(acc[0], acc[1]);
            u.i2[1] = packh2(acc[2], acc[3]);
            *(half4*)(sHalf + VRO + (mt4 * 16 + mrow) * 200 + h * 32 + t * 16 + kq * 4) = u.h4;
        }
    }

    // ---------------- Phase 1b: K then Q -> frags via per-wave scratch [32][40] ----------------
    half8 aK[4], bQ[4];
    #pragma unroll
    for (int qk = 0; qk < 2; ++qk) {            // 0 = K (nt 12+2h..), 1 = Q (nt 2h..)
        #pragma unroll
        for (int hf = 0; hf < 2; ++hf) {        // token halves: tiles 2hf, 2hf+1
            #pragma unroll
            for (int t = 0; t < 2; ++t) {
                int nt = (qk == 0 ? 12 : 0) + 2 * h + t;
                half8 bf[6];
                #pragma unroll
                for (int ks = 0; ks < 6; ++ks)
                    bf[ks] = ((const half8*)WtF)[(nt * 6 + ks) * 64 + lane];
                const float* bptr = (qk == 0) ? (bkv + nt * 16 - 192) : (bq + nt * 16);
                float4 b4 = *(const float4*)(bptr + kq * 4);
                floatx4 binit = {b4.x, b4.y, b4.z, b4.w};
                #pragma unroll
                for (int mt2 = 0; mt2 < 2; ++mt2) {
                    int mt4 = hf * 2 + mt2;
                    floatx4 acc = binit;
                    #pragma unroll
                    for (int ks = 0; ks < 6; ++ks) {
                        half8 af = *(const half8*)(sHalf + XO + (mt4 * 16 + mrow) * 200 + ks * 32 + kq * 8);
                        acc = __builtin_amdgcn_mfma_f32_16x16x32_f16(bf[ks], af, acc, 0, 0, 0);
                    }
                    if (qk == 1) {
                        acc[0] *= scale; acc[1] *= scale; acc[2] *= scale; acc[3] *= scale;
                    }
                    union { int i2[2]; half4 h4; } u;
                    u.i2[0] = packh2(acc[0], acc[1]);
                    u.i2[1] = packh2(acc[2], acc[3]);
                    *(half4*)(sS + (mt2 * 16 + mrow) * 40 + t * 16 + kq * 4) = u.h4;
                }
            }
            #pragma unroll
            for (int q2 = 0; q2 < 2; ++q2) {
                half8 f = *(const half8*)(sS + (q2 * 16 + mrow) * 40 + kq * 8);
                if (qk == 0) aK[hf * 2 + q2] = f;
                else         bQ[hf * 2 + q2] = f;
            }
        }
    }

    // ---------------- Phase 1c: V -> V^T frags via per-d-half scratch [16][72] -> regs ----------------
    half8 bV[2][2];
    #pragma unroll
    for (int t = 0; t < 2; ++t) {               // d-half = ntd
        int nt = 24 + 2 * h + t;
        half8 bf[6];
        #pragma unroll
        for (int ks = 0; ks < 6; ++ks)
            bf[ks] = ((const half8*)WtF)[(nt * 6 + ks) * 64 + lane];
        float bv = bkv[nt * 16 - 192 + mrow];
        #pragma unroll
        for (int mt = 0; mt < 4; ++mt) {
            floatx4 acc = {bv, bv, bv, bv};
            #pragma unroll
            for (int ks = 0; ks < 6; ++ks) {
                half8 af = *(const half8*)(sHalf + XO + (mt * 16 + mrow) * 200 + ks * 32 + kq * 8);
                acc = __builtin_amdgcn_mfma_f32_16x16x32_f16(af, bf[ks], acc, 0, 0, 0);
            }
            union { int i2[2]; half4 h4; } u;
            u.i2[0] = packh2(acc[0], acc[1]);
            u.i2[1] = packh2(acc[2], acc[3]);
            *(half4*)(sS + mrow * 72 + mt * 16 + kq * 4) = u.h4;
        }
        #pragma unroll
        for (int ks2 = 0; ks2 < 2; ++ks2)
            bV[t][ks2] = *(const half8*)(sS + mrow * 72 + ks2 * 32 + kq * 8);
    }

    // ---------------- Phase 2a: depthwise 5x5 on own sVR stripe ----------------
    const int cb32 = h * 32 + kq * 8;
    const half8* dwFp = (const half8*)dwF + (h * 4 + kq) * 25;
    H8 bini; bini.h8 = ((const half8*)dwbF)[h * 4 + kq];
    half2 cacc[4][4];
    #pragma unroll
    for (int mt = 0; mt < 4; ++mt)
        #pragma unroll
        for (int p = 0; p < 4; ++p) cacc[mt][p] = bini.h2[p];

    int ni[4], nj[4];
    #pragma unroll
    for (int mt = 0; mt < 4; ++mt) { int n = mt * 16 + mrow; ni[mt] = n >> 3; nj[mt] = n & 7; }

    #pragma unroll 5
    for (int t = 0; t < 25; ++t) {
        H8 wgt; wgt.h8 = dwFp[t];
        int di = t / 5 - 2, dj = t % 5 - 2;
        #pragma unroll
        for (int mt = 0; mt < 4; ++mt) {
            int ii = ni[mt] + di, jj = nj[mt] + dj;
            bool ok = ((unsigned)ii < 8u) & ((unsigned)jj < 8u);
            int off = ok ? (VRO + ((ii << 3) + jj) * 200 + cb32) : ZO;
            H8 d; d.h8 = *(const half8*)(sHalf + off);
            #pragma unroll
            for (int p = 0; p < 4; ++p) cacc[mt][p] += d.h2[p] * wgt.h2[p];
        }
    }
    half8 dwA[4];
    #pragma unroll
    for (int mt = 0; mt < 4; ++mt) {
        H8 u;
        #pragma unroll
        for (int p = 0; p < 4; ++p) u.h2[p] = cacc[mt][p];
        dwA[mt] = u.h8;
    }

    // ---------------- Phase 2b: grouped 1x1 (transposed); result f16 -> out_pre slot in sVR ----------------
    #pragma unroll
    for (int ntc = 0; ntc < 2; ++ntc) {
        half8 pwB = ((const half8*)pwF)[(h * 2 + ntc) * 64 + lane];
        float4 pb4 = *(const float4*)(pw_b + h * 32 + ntc * 16 + kq * 4);
        #pragma unroll
        for (int mt = 0; mt < 4; ++mt) {
            floatx4 acc = {pb4.x, pb4.y, pb4.z, pb4.w};
            acc = __builtin_amdgcn_mfma_f32_16x16x32_f16(pwB, dwA[mt], acc, 0, 0, 0);
            union { int i2[2]; half4 h4; } u;
            u.i2[0] = packh2(acc[0], acc[1]);
            u.i2[1] = packh2(acc[2], acc[3]);
            *(half4*)(sHalf + VRO + (mt * 16 + mrow) * 200 + h * 32 + ntc * 16 + kq * 4) = u.h4;
        }
    }

    // ---------------- Phase 3: attention, one q-tile (16 queries) at a time ----------------
    const int idxA = ((kq & 1) * 32 + mrow) * 4;
    const int idxB = idxA + 64;
    const bool sel = (kq >= 2);

    #pragma unroll
    for (int ntq = 0; ntq < 4; ++ntq) {
        // S^T = K . Q^T + bias  (16 regs of S^T)
        floatx4 stt[4];
        #pragma unroll
        for (int mtk = 0; mtk < 4; ++mtk) {
            floatx4 bb = *(const floatx4*)(biasF + (((h * 4 + mtk) * 4 + ntq) * 64 + lane) * 4);
            stt[mtk] = __builtin_amdgcn_mfma_f32_16x16x32_f16(aK[mtk], bQ[ntq], bb, 0, 0, 0);
        }

        // softmax over keys (16 per lane + shfl over kq bits)
        float mx = stt[0][0];
        #pragma unroll
        for (int mtk = 0; mtk < 4; ++mtk)
            #pragma unroll
            for (int r = 0; r < 4; ++r) mx = fmaxf(mx, stt[mtk][r]);
        mx = fmaxf(mx, __shfl_xor(mx, 16));
        mx = fmaxf(mx, __shfl_xor(mx, 32));
        float sm = 0.0f;
        #pragma unroll
        for (int mtk = 0; mtk < 4; ++mtk)
            #pragma unroll
            for (int r = 0; r < 4; ++r) {
                float e = __expf(stt[mtk][r] - mx);
                stt[mtk][r] = e;
                sm += e;
            }
        sm += __shfl_xor(sm, 16);
        sm += __shfl_xor(sm, 32);
        float inv = 1.0f / sm;

        // pack P^T pairs (stt dies here)
        int pk[4][2];
        #pragma unroll
        for (int mtk = 0; mtk < 4; ++mtk) {
            pk[mtk][0] = packh2(stt[mtk][0] * inv, stt[mtk][1] * inv);
            pk[mtk][1] = packh2(stt[mtk][2] * inv, stt[mtk][3] * inv);
        }

        // PV accumulators seeded from conv output (readback from out_pre slot)
        floatx4 acc[2];
        #pragma unroll
        for (int ntd = 0; ntd < 2; ++ntd) {
            union { half4 h4; int i2[2]; } u;
            u.h4 = *(const half4*)(sHalf + VRO + (ntq * 16 + mrow) * 200 + h * 32 + ntd * 16 + kq * 4);
            acc[ntd] = unpack4(u.i2[0], u.i2[1]);
        }

        #pragma unroll
        for (int ks2 = 0; ks2 < 2; ++ks2) {
            half8 aP = gather8(idxA, idxB, sel,
                               pk[2 * ks2][0],     pk[2 * ks2][1],
                               pk[2 * ks2 + 1][0], pk[2 * ks2 + 1][1]);
            #pragma unroll
            for (int ntd = 0; ntd < 2; ++ntd)
                acc[ntd] = __builtin_amdgcn_mfma_f32_16x16x32_f16(bV[ntd][ks2], aP, acc[ntd], 0, 0, 0);
        }

        // out_pre rows for this q-tile into own sVR stripe (half4 writes)
        #pragma unroll
        for (int ntd = 0; ntd < 2; ++ntd) {
            floatx4 o = acc[ntd];
            union { int i2[2]; half4 h4; } u;
            u.i2[0] = packh2(o[0], o[1]);
            u.i2[1] = packh2(o[2], o[3]);
            *(half4*)(sHalf + VRO + (ntq * 16 + mrow) * 200 + h * 32 + ntd * 16 + kq * 4) = u.h4;
        }
    }
    __syncthreads();   // barrier 2

    // ---------------- Phase 4: proj GEMM (M=64, N=192, K=192), direct f32 stores ----------------
    float* og = outg + (size_t)b2 * 12288;
    #pragma unroll
    for (int tnt = 0; tnt < 2; ++tnt) {
        int nt = 2 * h + tnt;
        half8 bf[6];
        #pragma unroll
        for (int ks = 0; ks < 6; ++ks)
            bf[ks] = ((const half8*)PtF)[(nt * 6 + ks) * 64 + lane];
        float bv = proj_bg[nt * 16 + mrow];
        #pragma unroll
        for (int mt = 0; mt < 4; ++mt) {
            floatx4 acc = {bv, bv, bv, bv};
            #pragma unroll
            for (int ks = 0; ks < 6; ++ks) {
                half8 af = *(const half8*)(sHalf + VRO + (mt * 16 + mrow) * 200 + ks * 32 + kq * 8);
                acc = __builtin_amdgcn_mfma_f32_16x16x32_f16(af, bf[ks], acc, 0, 0, 0);
            }
            int m0 = mt * 16 + kq * 4;
            #pragma unroll
            for (int r = 0; r < 4; ++r)
                og[(m0 + r) * 192 + nt * 16 + mrow] = acc[r];
        }
    }
}

extern "C" void kernel_launch(void* const* d_in, const int* in_sizes, int n_in,
                              void* d_out, int out_size, void* d_ws, size_t ws_size,
                              hipStream_t stream) {
    (void)in_sizes; (void)n_in; (void)out_size; (void)ws_size;
    const float* x      = (const float*)d_in[0];
    const float* wq     = (const float*)d_in[1];
    const float* bq     = (const float*)d_in[2];
    const float* wkv    = (const float*)d_in[3];
    const float* bkv    = (const float*)d_in[4];
    const float* rpb    = (const float*)d_in[5];
    const int*   rel    = (const int*)d_in[6];
    const float* dw_w   = (const float*)d_in[7];
    const float* dw_b   = (const float*)d_in[8];
    const float* pw_w   = (const float*)d_in[9];
    const float* pw_b   = (const float*)d_in[10];
    const float* proj_w = (const float*)d_in[11];
    const float* proj_b = (const float*)d_in[12];

    _Float16* WtF  = (_Float16*)d_ws;
    _Float16* PtF  = (_Float16*)((char*)d_ws + 294912);
    float*    biasF= (float*)((char*)d_ws + 368640);
    _Float16* dwF  = (_Float16*)((char*)d_ws + 466944);
    _Float16* dwbF = (_Float16*)((char*)d_ws + 476544);
    _Float16* pwF  = (_Float16*)((char*)d_ws + 476928);

    prep_kernel<<<430, 512, 0, stream>>>(wq, wkv, proj_w, rpb, rel, dw_w, dw_b, pw_w,
                                         WtF, PtF, biasF, dwF, dwbF, pwF);
    wa_main<<<2048, 768, 0, stream>>>(x, bq, bkv, proj_b, pw_b,
                                      WtF, PtF, biasF, dwF, dwbF, pwF,
                                      (float*)d_out);
}

// Round 10
// 573.894 us; speedup vs baseline: 1.0262x; 1.0262x over previous
//
#include <hip/hip_runtime.h>

typedef _Float16 half8 __attribute__((ext_vector_type(8)));
typedef _Float16 half4 __attribute__((ext_vector_type(4)));
typedef _Float16 half2 __attribute__((ext_vector_type(2)));
typedef float floatx4 __attribute__((ext_vector_type(4)));

union H8 { half8 h8; half4 h4[2]; half2 h2[4]; int i[4]; };

__device__ __forceinline__ int packh2(float a, float b) {
    union { _Float16 h[2]; int i; } u;
    u.h[0] = (_Float16)a; u.h[1] = (_Float16)b;
    return u.i;
}

__device__ __forceinline__ floatx4 unpack4(int lo, int hi) {
    union { int i; _Float16 h[2]; } a, b;
    a.i = lo; b.i = hi;
    floatx4 r = {(float)a.h[0], (float)a.h[1], (float)b.h[0], (float)b.h[1]};
    return r;
}

// Gather a half8 A-fragment from per-lane packed P pairs (proven P-repack path).
__device__ __forceinline__ half8 gather8(int idxA, int idxB, bool sel,
                                         int A0, int A1, int B0, int B1) {
    int a0 = __builtin_amdgcn_ds_bpermute(idxA, A0);
    int b0 = __builtin_amdgcn_ds_bpermute(idxA, B0);
    int a1 = __builtin_amdgcn_ds_bpermute(idxA, A1);
    int b1 = __builtin_amdgcn_ds_bpermute(idxA, B1);
    int a2 = __builtin_amdgcn_ds_bpermute(idxB, A0);
    int b2 = __builtin_amdgcn_ds_bpermute(idxB, B0);
    int a3 = __builtin_amdgcn_ds_bpermute(idxB, A1);
    int b3 = __builtin_amdgcn_ds_bpermute(idxB, B1);
    H8 u;
    u.i[0] = sel ? b0 : a0;
    u.i[1] = sel ? b1 : a1;
    u.i[2] = sel ? b2 : a2;
    u.i[3] = sel ? b3 : a3;
    return u.h8;
}

// Problem constants: B=4096 windows, N=64 tokens (8x8), C=192, NH=6, HD=32, KS=5
//
// ws layout (bytes) -- everything pre-swizzled into MFMA fragment order:
//   WtF  : f16 [48 nt][6 ks][64 lane][8]  @ 0       (294912 B)  qkv weights (B-frags)
//   PtF  : f16 [12 nt][6 ks][64 lane][8]  @ 294912  ( 73728 B)  proj weights (B-frags)
//   biasF: f32 [6 h][4 mt'][4 ntq][64 lane][4 r] @ 368640 (98304 B)  attn bias in S^T C-frag order
//   dwF  : f16 [6 g][4 kq][25 tap][8 ch]  @ 466944  (  9600 B)  depthwise weights
//   dwbF : f16 [6 g][4 kq][8 ch]          @ 476544  (   384 B)  depthwise bias
//   pwF  : f16 [6 g][2 ntc][64 lane][8]   @ 476928  ( 12288 B)  1x1 grouped weights (B-frags)

__global__ __launch_bounds__(512) void prep_kernel(
    const float* __restrict__ wq, const float* __restrict__ wkv,
    const float* __restrict__ proj_w, const float* __restrict__ rpb,
    const int* __restrict__ rel,
    const float* __restrict__ dw_w, const float* __restrict__ dw_b,
    const float* __restrict__ pw_w,
    _Float16* __restrict__ WtF, _Float16* __restrict__ PtF,
    float* __restrict__ biasF, _Float16* __restrict__ dwF,
    _Float16* __restrict__ dwbF, _Float16* __restrict__ pwF)
{
    int idx = blockIdx.x * 512 + threadIdx.x;
    if (idx < 147456) {                                   // WtF
        int j = idx & 7, lane = (idx >> 3) & 63, t = idx >> 9;
        int ks = t % 6, nt = t / 6;
        int k = ks * 32 + (lane >> 4) * 8 + j;
        int n = nt * 16 + (lane & 15);
        float v = (n < 192) ? wq[k * 192 + n] : wkv[k * 576 + (n - 192)];
        WtF[idx] = (_Float16)v;
    } else if (idx < 184320) {                            // PtF
        int i2 = idx - 147456;
        int j = i2 & 7, lane = (i2 >> 3) & 63, t = i2 >> 9;
        int ks = t % 6, nt = t / 6;
        int k = ks * 32 + (lane >> 4) * 8 + j;
        int n = nt * 16 + (lane & 15);
        PtF[i2] = (_Float16)proj_w[k * 192 + n];
    } else if (idx < 208896) {                            // biasF (f32)
        int i2 = idx - 184320;
        int r = i2 & 3, lane = (i2 >> 2) & 63, t = i2 >> 8;
        int ntq = t & 3, mt = (t >> 2) & 3, h = t >> 4;
        int m = mt * 16 + (lane >> 4) * 4 + r;            // key token (S^T row)
        int n = ntq * 16 + (lane & 15);                   // query token (S^T col)
        biasF[i2] = rpb[rel[n * 64 + m] * 6 + h];
    } else if (idx < 213696) {                            // dwF
        int i2 = idx - 208896;
        int j = i2 & 7, t = i2 >> 3;
        int tap = t % 25, gk = t / 25;
        int c = (gk >> 2) * 32 + (gk & 3) * 8 + j;
        dwF[i2] = (_Float16)dw_w[c * 25 + tap];
    } else if (idx < 213888) {                            // dwbF
        int i2 = idx - 213696;
        int j = i2 & 7, gk = i2 >> 3;
        int c = (gk >> 2) * 32 + (gk & 3) * 8 + j;
        dwbF[i2] = (_Float16)dw_b[c];
    } else if (idx < 220032) {                            // pwF
        int i2 = idx - 213888;
        int j = i2 & 7, lane = (i2 >> 3) & 63, t = i2 >> 9;
        int ntc = t & 1, g = t >> 1;
        int oc = g * 32 + ntc * 16 + (lane & 15);
        int ic = (lane >> 4) * 8 + j;
        pwF[i2] = (_Float16)pw_w[oc * 32 + ic];
    }
}

// TWO WINDOWS PER BLOCK (768 threads = 12 waves = forced 3 waves/SIMD on one CU).
// Waves 0-5 -> window 2b, waves 6-11 -> window 2b+1, each in its own LDS partition.
//
// Per-window LDS partition (_Float16 units, stride WSTR = 37896):
//  sX    [64][200] @ 0      (12800 h) x staged f16
//  sVR   [64][200] @ 12800  (12800 h) v_r[n][c]; conv output + out_pre land here too
//  sS    6 x 2048  @ 25600  (12288 h) per-wave: transient K [32][40] / V [16][72],
//                                     then Q RESIDENT packed [64][32] (2048 h)
//  zero16          @ 37888  (8 h)
// total = 2 x 37896 h = 151584 B static (under 160 KiB).
//
// Register-cap accommodation: the backend pins VGPR=84 for wg>=512 (6-waves/EU
// budget step) regardless of LDS-derived occupancy -- proven R7(extern)/R9(static
// both 84 + spills). So instead of raising the cap we FIT it: Q moves from 16
// registers to a per-wave LDS-resident packed region (produced last, after K/V
// transients are dead; same-wave in-order DS). Peak live ~= aK16+bV16+bQ8+stt16
// +acc8+temps ~= 80-88, at the 84 cap -> spills collapse.

#define WSTR 37896
#define XO   0
#define VRO  12800
#define SCR  25600
#define ZO   37888

__global__ __launch_bounds__(768) void wa_main(
    const float* __restrict__ xg,
    const float* __restrict__ bq, const float* __restrict__ bkv,
    const float* __restrict__ proj_bg, const float* __restrict__ pw_b,
    const _Float16* __restrict__ WtF, const _Float16* __restrict__ PtF,
    const float* __restrict__ biasF,
    const _Float16* __restrict__ dwF, const _Float16* __restrict__ dwbF,
    const _Float16* __restrict__ pwF,
    float* __restrict__ outg)
{
    __shared__ _Float16 smem[2 * WSTR];   // 151584 B static LDS

    const int tid  = threadIdx.x;
    const int lane = tid & 63;
    const int wvid = tid >> 6;          // 0..11
    const int w    = (wvid >= 6) ? 1 : 0;   // window slot within block
    const int h    = wvid - 6 * w;      // head 0..5
    const int b2   = blockIdx.x * 2 + w;
    const int tw   = tid - w * 384;     // thread id within window group
    const int mrow = lane & 15;
    const int kq   = lane >> 4;
    const float scale = 0.17677669529663687f;   // 32^-0.5

    _Float16* sHalf = smem + w * WSTR;          // this window's partition
    _Float16* sS = sHalf + SCR + h * 2048;      // this wave's scratch / Q-resident

    // ---------------- Phase 0: stage x -> f16 LDS; zero page ----------------
    const float* xb = xg + (size_t)b2 * 12288;
    #pragma unroll
    for (int it = 0; it < 8; ++it) {
        int f4  = it * 384 + tw;
        int row = f4 / 48;
        int col = (f4 % 48) * 4;
        float4 v = ((const float4*)xb)[f4];
        half4 p;
        p[0] = (_Float16)v.x; p[1] = (_Float16)v.y;
        p[2] = (_Float16)v.z; p[3] = (_Float16)v.w;
        *(half4*)(sHalf + XO + row * 200 + col) = p;
    }
    if (tw < 8) sHalf[ZO + tw] = (_Float16)0.0f;
    __syncthreads();   // barrier 1 (both windows; identical work -> minimal skew)

    // ---------------- Phase 1a: v_r (swapped mfma -> transposed D -> half4 stores) ----------------
    #pragma unroll
    for (int t = 0; t < 2; ++t) {
        int nt = 36 + 2 * h + t;
        half8 bf[6];
        #pragma unroll
        for (int ks = 0; ks < 6; ++ks)
            bf[ks] = ((const half8*)WtF)[(nt * 6 + ks) * 64 + lane];
        float4 b4 = *(const float4*)(bkv + nt * 16 - 192 + kq * 4);
        floatx4 binit = {b4.x, b4.y, b4.z, b4.w};
        #pragma unroll
        for (int mt4 = 0; mt4 < 4; ++mt4) {
            floatx4 acc = binit;
            #pragma unroll
            for (int ks = 0; ks < 6; ++ks) {
                half8 af = *(const half8*)(sHalf + XO + (mt4 * 16 + mrow) * 200 + ks * 32 + kq * 8);
                acc = __builtin_amdgcn_mfma_f32_16x16x32_f16(bf[ks], af, acc, 0, 0, 0);
            }
            union { int i2[2]; half4 h4; } u;
            u.i2[0] = packh2(acc[0], acc[1]);
            u.i2[1] = packh2(acc[2], acc[3]);
            *(half4*)(sHalf + VRO + (mt4 * 16 + mrow) * 200 + h * 32 + t * 16 + kq * 4) = u.h4;
        }
    }

    // ---------------- Phase 1b: K -> aK regs via transient scratch [32][40] ----------------
    half8 aK[4];
    #pragma unroll
    for (int hf = 0; hf < 2; ++hf) {            // token halves: tiles 2hf, 2hf+1
        #pragma unroll
        for (int t = 0; t < 2; ++t) {
            int nt = 12 + 2 * h + t;
            half8 bf[6];
            #pragma unroll
            for (int ks = 0; ks < 6; ++ks)
                bf[ks] = ((const half8*)WtF)[(nt * 6 + ks) * 64 + lane];
            float4 b4 = *(const float4*)(bkv + nt * 16 - 192 + kq * 4);
            floatx4 binit = {b4.x, b4.y, b4.z, b4.w};
            #pragma unroll
            for (int mt2 = 0; mt2 < 2; ++mt2) {
                int mt4 = hf * 2 + mt2;
                floatx4 acc = binit;
                #pragma unroll
                for (int ks = 0; ks < 6; ++ks) {
                    half8 af = *(const half8*)(sHalf + XO + (mt4 * 16 + mrow) * 200 + ks * 32 + kq * 8);
                    acc = __builtin_amdgcn_mfma_f32_16x16x32_f16(bf[ks], af, acc, 0, 0, 0);
                }
                union { int i2[2]; half4 h4; } u;
                u.i2[0] = packh2(acc[0], acc[1]);
                u.i2[1] = packh2(acc[2], acc[3]);
                *(half4*)(sS + (mt2 * 16 + mrow) * 40 + t * 16 + kq * 4) = u.h4;
            }
        }
        #pragma unroll
        for (int q2 = 0; q2 < 2; ++q2)
            aK[hf * 2 + q2] = *(const half8*)(sS + (q2 * 16 + mrow) * 40 + kq * 8);
    }

    // ---------------- Phase 1c: V -> bV regs via transient scratch [16][72] ----------------
    half8 bV[2][2];
    #pragma unroll
    for (int t = 0; t < 2; ++t) {               // d-half = ntd
        int nt = 24 + 2 * h + t;
        half8 bf[6];
        #pragma unroll
        for (int ks = 0; ks < 6; ++ks)
            bf[ks] = ((const half8*)WtF)[(nt * 6 + ks) * 64 + lane];
        float bv = bkv[nt * 16 - 192 + mrow];
        #pragma unroll
        for (int mt = 0; mt < 4; ++mt) {
            floatx4 acc = {bv, bv, bv, bv};
            #pragma unroll
            for (int ks = 0; ks < 6; ++ks) {
                half8 af = *(const half8*)(sHalf + XO + (mt * 16 + mrow) * 200 + ks * 32 + kq * 8);
                acc = __builtin_amdgcn_mfma_f32_16x16x32_f16(af, bf[ks], acc, 0, 0, 0);
            }
            union { int i2[2]; half4 h4; } u;
            u.i2[0] = packh2(acc[0], acc[1]);
            u.i2[1] = packh2(acc[2], acc[3]);
            *(half4*)(sS + mrow * 72 + mt * 16 + kq * 4) = u.h4;
        }
        #pragma unroll
        for (int ks2 = 0; ks2 < 2; ++ks2)
            bV[t][ks2] = *(const half8*)(sS + mrow * 72 + ks2 * 32 + kq * 8);
    }

    // ---------------- Phase 1d: Q -> LDS-RESIDENT packed [64][32] (transients now dead) ----------------
    #pragma unroll
    for (int hf = 0; hf < 2; ++hf) {
        #pragma unroll
        for (int t = 0; t < 2; ++t) {
            int nt = 2 * h + t;
            half8 bf[6];
            #pragma unroll
            for (int ks = 0; ks < 6; ++ks)
                bf[ks] = ((const half8*)WtF)[(nt * 6 + ks) * 64 + lane];
            float4 b4 = *(const float4*)(bq + nt * 16 + kq * 4);
            floatx4 binit = {b4.x, b4.y, b4.z, b4.w};
            #pragma unroll
            for (int mt2 = 0; mt2 < 2; ++mt2) {
                int mt4 = hf * 2 + mt2;
                floatx4 acc = binit;
                #pragma unroll
                for (int ks = 0; ks < 6; ++ks) {
                    half8 af = *(const half8*)(sHalf + XO + (mt4 * 16 + mrow) * 200 + ks * 32 + kq * 8);
                    acc = __builtin_amdgcn_mfma_f32_16x16x32_f16(bf[ks], af, acc, 0, 0, 0);
                }
                union { int i2[2]; half4 h4; } u;
                u.i2[0] = packh2(acc[0] * scale, acc[1] * scale);
                u.i2[1] = packh2(acc[2] * scale, acc[3] * scale);
                *(half4*)(sS + (hf * 32 + mt2 * 16 + mrow) * 32 + t * 16 + kq * 4) = u.h4;
            }
        }
    }

    // ---------------- Phase 2a: depthwise 5x5 on own sVR stripe ----------------
    const int cb32 = h * 32 + kq * 8;
    const half8* dwFp = (const half8*)dwF + (h * 4 + kq) * 25;
    H8 bini; bini.h8 = ((const half8*)dwbF)[h * 4 + kq];
    half2 cacc[4][4];
    #pragma unroll
    for (int mt = 0; mt < 4; ++mt)
        #pragma unroll
        for (int p = 0; p < 4; ++p) cacc[mt][p] = bini.h2[p];

    int ni[4], nj[4];
    #pragma unroll
    for (int mt = 0; mt < 4; ++mt) { int n = mt * 16 + mrow; ni[mt] = n >> 3; nj[mt] = n & 7; }

    #pragma unroll 5
    for (int t = 0; t < 25; ++t) {
        H8 wgt; wgt.h8 = dwFp[t];
        int di = t / 5 - 2, dj = t % 5 - 2;
        #pragma unroll
        for (int mt = 0; mt < 4; ++mt) {
            int ii = ni[mt] + di, jj = nj[mt] + dj;
            bool ok = ((unsigned)ii < 8u) & ((unsigned)jj < 8u);
            int off = ok ? (VRO + ((ii << 3) + jj) * 200 + cb32) : ZO;
            H8 d; d.h8 = *(const half8*)(sHalf + off);
            #pragma unroll
            for (int p = 0; p < 4; ++p) cacc[mt][p] += d.h2[p] * wgt.h2[p];
        }
    }
    half8 dwA[4];
    #pragma unroll
    for (int mt = 0; mt < 4; ++mt) {
        H8 u;
        #pragma unroll
        for (int p = 0; p < 4; ++p) u.h2[p] = cacc[mt][p];
        dwA[mt] = u.h8;
    }

    // ---------------- Phase 2b: grouped 1x1 (transposed); result f16 -> out_pre slot in sVR ----------------
    #pragma unroll
    for (int ntc = 0; ntc < 2; ++ntc) {
        half8 pwB = ((const half8*)pwF)[(h * 2 + ntc) * 64 + lane];
        float4 pb4 = *(const float4*)(pw_b + h * 32 + ntc * 16 + kq * 4);
        #pragma unroll
        for (int mt = 0; mt < 4; ++mt) {
            floatx4 acc = {pb4.x, pb4.y, pb4.z, pb4.w};
            acc = __builtin_amdgcn_mfma_f32_16x16x32_f16(pwB, dwA[mt], acc, 0, 0, 0);
            union { int i2[2]; half4 h4; } u;
            u.i2[0] = packh2(acc[0], acc[1]);
            u.i2[1] = packh2(acc[2], acc[3]);
            *(half4*)(sHalf + VRO + (mt * 16 + mrow) * 200 + h * 32 + ntc * 16 + kq * 4) = u.h4;
        }
    }

    // ---------------- Phase 3: attention, one q-tile (16 queries) at a time ----------------
    const int idxA = ((kq & 1) * 32 + mrow) * 4;
    const int idxB = idxA + 64;
    const bool sel = (kq >= 2);

    #pragma unroll
    for (int ntq = 0; ntq < 4; ++ntq) {
        // Q fragment for this tile from LDS-resident packed region
        half8 bQv = *(const half8*)(sS + (ntq * 16 + mrow) * 32 + kq * 8);

        // S^T = K . Q^T + bias  (16 regs of S^T)
        floatx4 stt[4];
        #pragma unroll
        for (int mtk = 0; mtk < 4; ++mtk) {
            floatx4 bb = *(const floatx4*)(biasF + (((h * 4 + mtk) * 4 + ntq) * 64 + lane) * 4);
            stt[mtk] = __builtin_amdgcn_mfma_f32_16x16x32_f16(aK[mtk], bQv, bb, 0, 0, 0);
        }

        // softmax over keys (16 per lane + shfl over kq bits)
        float mx = stt[0][0];
        #pragma unroll
        for (int mtk = 0; mtk < 4; ++mtk)
            #pragma unroll
            for (int r = 0; r < 4; ++r) mx = fmaxf(mx, stt[mtk][r]);
        mx = fmaxf(mx, __shfl_xor(mx, 16));
        mx = fmaxf(mx, __shfl_xor(mx, 32));
        float sm = 0.0f;
        #pragma unroll
        for (int mtk = 0; mtk < 4; ++mtk)
            #pragma unroll
            for (int r = 0; r < 4; ++r) {
                float e = __expf(stt[mtk][r] - mx);
                stt[mtk][r] = e;
                sm += e;
            }
        sm += __shfl_xor(sm, 16);
        sm += __shfl_xor(sm, 32);
        float inv = 1.0f / sm;

        // pack P^T pairs (stt dies here)
        int pk[4][2];
        #pragma unroll
        for (int mtk = 0; mtk < 4; ++mtk) {
            pk[mtk][0] = packh2(stt[mtk][0] * inv, stt[mtk][1] * inv);
            pk[mtk][1] = packh2(stt[mtk][2] * inv, stt[mtk][3] * inv);
        }

        // PV accumulators seeded from conv output (readback from out_pre slot)
        floatx4 acc[2];
        #pragma unroll
        for (int ntd = 0; ntd < 2; ++ntd) {
            union { half4 h4; int i2[2]; } u;
            u.h4 = *(const half4*)(sHalf + VRO + (ntq * 16 + mrow) * 200 + h * 32 + ntd * 16 + kq * 4);
            acc[ntd] = unpack4(u.i2[0], u.i2[1]);
        }

        #pragma unroll
        for (int ks2 = 0; ks2 < 2; ++ks2) {
            half8 aP = gather8(idxA, idxB, sel,
                               pk[2 * ks2][0],     pk[2 * ks2][1],
                               pk[2 * ks2 + 1][0], pk[2 * ks2 + 1][1]);
            #pragma unroll
            for (int ntd = 0; ntd < 2; ++ntd)
                acc[ntd] = __builtin_amdgcn_mfma_f32_16x16x32_f16(bV[ntd][ks2], aP, acc[ntd], 0, 0, 0);
        }

        // out_pre rows for this q-tile into own sVR stripe (half4 writes)
        #pragma unroll
        for (int ntd = 0; ntd < 2; ++ntd) {
            floatx4 o = acc[ntd];
            union { int i2[2]; half4 h4; } u;
            u.i2[0] = packh2(o[0], o[1]);
            u.i2[1] = packh2(o[2], o[3]);
            *(half4*)(sHalf + VRO + (ntq * 16 + mrow) * 200 + h * 32 + ntd * 16 + kq * 4) = u.h4;
        }
    }
    __syncthreads();   // barrier 2

    // ---------------- Phase 4: proj GEMM (M=64, N=192, K=192), direct f32 stores ----------------
    float* og = outg + (size_t)b2 * 12288;
    #pragma unroll
    for (int tnt = 0; tnt < 2; ++tnt) {
        int nt = 2 * h + tnt;
        half8 bf[6];
        #pragma unroll
        for (int ks = 0; ks < 6; ++ks)
            bf[ks] = ((const half8*)PtF)[(nt * 6 + ks) * 64 + lane];
        float bv = proj_bg[nt * 16 + mrow];
        #pragma unroll
        for (int mt = 0; mt < 4; ++mt) {
            floatx4 acc = {bv, bv, bv, bv};
            #pragma unroll
            for (int ks = 0; ks < 6; ++ks) {
                half8 af = *(const half8*)(sHalf + VRO + (mt * 16 + mrow) * 200 + ks * 32 + kq * 8);
                acc = __builtin_amdgcn_mfma_f32_16x16x32_f16(af, bf[ks], acc, 0, 0, 0);
            }
            int m0 = mt * 16 + kq * 4;
            #pragma unroll
            for (int r = 0; r < 4; ++r)
                og[(m0 + r) * 192 + nt * 16 + mrow] = acc[r];
        }
    }
}

extern "C" void kernel_launch(void* const* d_in, const int* in_sizes, int n_in,
                              void* d_out, int out_size, void* d_ws, size_t ws_size,
                              hipStream_t stream) {
    (void)in_sizes; (void)n_in; (void)out_size; (void)ws_size;
    const float* x      = (const float*)d_in[0];
    const float* wq     = (const float*)d_in[1];
    const float* bq     = (const float*)d_in[2];
    const float* wkv    = (const float*)d_in[3];
    const float* bkv    = (const float*)d_in[4];
    const float* rpb    = (const float*)d_in[5];
    const int*   rel    = (const int*)d_in[6];
    const float* dw_w   = (const float*)d_in[7];
    const float* dw_b   = (const float*)d_in[8];
    const float* pw_w   = (const float*)d_in[9];
    const float* pw_b   = (const float*)d_in[10];
    const float* proj_w = (const float*)d_in[11];
    const float* proj_b = (const float*)d_in[12];

    _Float16* WtF  = (_Float16*)d_ws;
    _Float16* PtF  = (_Float16*)((char*)d_ws + 294912);
    float*    biasF= (float*)((char*)d_ws + 368640);
    _Float16* dwF  = (_Float16*)((char*)d_ws + 466944);
    _Float16* dwbF = (_Float16*)((char*)d_ws + 476544);
    _Float16* pwF  = (_Float16*)((char*)d_ws + 476928);

    prep_kernel<<<430, 512, 0, stream>>>(wq, wkv, proj_w, rpb, rel, dw_w, dw_b, pw_w,
                                         WtF, PtF, biasF, dwF, dwbF, pwF);
    wa_main<<<2048, 768, 0, stream>>>(x, bq, bkv, proj_b, pw_b,
                                      WtF, PtF, biasF, dwF, dwbF, pwF,
                                      (float*)d_out);
}